// Round 2
// baseline (1890.818 us; speedup 1.0000x reference)
//
#include <hip/hip_runtime.h>
#include <cstdint>

// Fast activations: ~2-ulp exp/div is plenty vs the 1e-3 absmax threshold.
__device__ __forceinline__ float fsig(float x) {
  x = fminf(fmaxf(x, -30.f), 30.f);
  return __fdividef(1.f, 1.f + __expf(-x));
}
__device__ __forceinline__ float ftanh_(float x) {
  x = fminf(fmaxf(x, -15.f), 15.f);
  float e = __expf(2.f * x);
  return __fdividef(e - 1.f, e + 1.f);
}

// Wave-wide broadcast from a lane's VGPR via v_readlane (VALU pipe, no LDS).
__device__ __forceinline__ float rl(float v, int lane) {
  return __int_as_float(__builtin_amdgcn_readlane(__float_as_int(v), lane));
}

// ---------------------------------------------------------------------------
// Layer 1: 262144 independent LSTM chains, seq=16, input=1, hidden=8.
// One chain per thread. Weights broadcast from LDS. (Unchanged this round.)
// ---------------------------------------------------------------------------
__global__ __launch_bounds__(256) void lstm1_kernel(
    const float* __restrict__ x, const float* __restrict__ Wih,
    const float* __restrict__ Whh, const float* __restrict__ bih,
    const float* __restrict__ bhh, float* __restrict__ h1) {
  __shared__ float sWih[32], sB[32], sWhh[256];
  const int tid = threadIdx.x;
  if (tid < 32) { sWih[tid] = Wih[tid]; sB[tid] = bih[tid] + bhh[tid]; }
  sWhh[tid] = Whh[tid];
  __syncthreads();

  const int n = blockIdx.x * 256 + tid;  // chain id = b*S + s
  const float4* xp = (const float4*)(x + (size_t)n * 16);
  float4 xa = xp[0], xb = xp[1], xc = xp[2], xd = xp[3];
  float xv[16] = {xa.x, xa.y, xa.z, xa.w, xb.x, xb.y, xb.z, xb.w,
                  xc.x, xc.y, xc.z, xc.w, xd.x, xd.y, xd.z, xd.w};
  float h[8] = {0, 0, 0, 0, 0, 0, 0, 0};
  float c[8] = {0, 0, 0, 0, 0, 0, 0, 0};

#pragma unroll
  for (int t = 0; t < 16; ++t) {
    float g[32];
#pragma unroll
    for (int r = 0; r < 32; ++r) {
      float a = fmaf(sWih[r], xv[t], sB[r]);
#pragma unroll
      for (int k = 0; k < 8; ++k) a = fmaf(sWhh[r * 8 + k], h[k], a);
      g[r] = a;
    }
#pragma unroll
    for (int k = 0; k < 8; ++k) {
      float iv = fsig(g[k]);
      float fv = fsig(g[8 + k]);
      float gv = ftanh_(g[16 + k]);
      float ov = fsig(g[24 + k]);
      c[k] = fmaf(fv, c[k], iv * gv);
      h[k] = ov * ftanh_(c[k]);
    }
  }
  float4* op = (float4*)(h1 + (size_t)n * 8);
  op[0] = make_float4(h[0], h[1], h[2], h[3]);
  op[1] = make_float4(h[4], h[5], h[6], h[7]);
}

// ---------------------------------------------------------------------------
// Layer 2: B=256 independent recurrences -> 1 block per CU.
// 256 threads (4 waves, 1/SIMD), thread t owns gate rows t and t+256.
// Weights in real VGPRs (no pointer punning -> SROA keeps them).
// h broadcast via v_readlane from per-wave float2-distributed registers
// (VALU pipe) instead of LDS broadcast reads (which were the R1 bottleneck).
// x-part reads are wave-uniform -> scalar loads, off the LDS/VALU pipes.
// ---------------------------------------------------------------------------
__global__ __launch_bounds__(256, 1) void lstm2_kernel(
    const float* __restrict__ h1, const float* __restrict__ Wih,
    const float* __restrict__ Whh, const float* __restrict__ bih,
    const float* __restrict__ bhh, const float* __restrict__ W1,
    const float* __restrict__ b1, const float* __restrict__ W2,
    const float* __restrict__ b2, float* __restrict__ out) {
  __shared__ float2 sGp[256];  // [t] = (act(row t), act(row t+256))
  __shared__ float sH[128];
  const int b = blockIdx.x;
  const int t = threadIdx.x;
  const int lane = t & 63;
  const int r0 = t;        // row t:      i (t<128) or f (t>=128)
  const int r1 = t + 256;  // row t+256:  g (t<128) or o (t>=128)
  const bool lo_half = (t < 128);  // wave-uniform (waves 0,1 vs 2,3)

  // --- load both weight rows into registers (scalar component assigns; no
  // pointer punning so SROA promotes the arrays) ---
  float w0[128], w1[128];
  {
    const float4* Wr0 = (const float4*)(Whh + (size_t)r0 * 128);
    const float4* Wr1 = (const float4*)(Whh + (size_t)r1 * 128);
#pragma unroll
    for (int i = 0; i < 32; ++i) {
      float4 v = Wr0[i];
      w0[4 * i] = v.x; w0[4 * i + 1] = v.y; w0[4 * i + 2] = v.z; w0[4 * i + 3] = v.w;
      float4 u = Wr1[i];
      w1[4 * i] = u.x; w1[4 * i + 1] = u.y; w1[4 * i + 2] = u.z; w1[4 * i + 3] = u.w;
    }
  }
  float wi0[8], wi1[8];
  {
    const float4* I0 = (const float4*)(Wih + (size_t)r0 * 8);
    const float4* I1 = (const float4*)(Wih + (size_t)r1 * 8);
    float4 a = I0[0], bb = I0[1], cc = I1[0], dd = I1[1];
    wi0[0] = a.x; wi0[1] = a.y; wi0[2] = a.z; wi0[3] = a.w;
    wi0[4] = bb.x; wi0[5] = bb.y; wi0[6] = bb.z; wi0[7] = bb.w;
    wi1[0] = cc.x; wi1[1] = cc.y; wi1[2] = cc.z; wi1[3] = cc.w;
    wi1[4] = dd.x; wi1[5] = dd.y; wi1[6] = dd.z; wi1[7] = dd.w;
  }
  const float bias0 = bih[r0] + bhh[r0];
  const float bias1 = bih[r1] + bhh[r1];

  const float* __restrict__ xbase = h1 + (size_t)b * 8192;  // [1024][8]

  float c = 0.f;                       // cell state, owned by t<128
  float2 vh = make_float2(0.f, 0.f);   // lane holds h[2*lane], h[2*lane+1]

  for (int tstep = 0; tstep < 1024; ++tstep) {
    // x-part: wave-uniform addresses -> scalar loads
    const float* xt = xbase + tstep * 8;
    float a0 = bias0, a1 = 0.f, b0 = bias1, b1v = 0.f;
#pragma unroll
    for (int j = 0; j < 8; ++j) {
      float xj = xt[j];
      a0 = fmaf(wi0[j], xj, a0);
      b0 = fmaf(wi1[j], xj, b0);
    }
    // h-part: readlane broadcast, each broadcast feeds both rows
#pragma unroll
    for (int k = 0; k < 128; k += 2) {
      float h0 = rl(vh.x, k >> 1);
      float h1v = rl(vh.y, k >> 1);
      a0 = fmaf(w0[k], h0, a0);
      b0 = fmaf(w1[k], h0, b0);
      a1 = fmaf(w0[k + 1], h1v, a1);
      b1v = fmaf(w1[k + 1], h1v, b1v);
    }
    float g0 = a0 + a1;  // row r0 pre-activation
    float g1 = b0 + b1v; // row r1 pre-activation
    // r0 is always a sigmoid gate (i or f); r1 is tanh (g) for waves 0,1
    // and sigmoid (o) for waves 2,3 — wave-uniform select.
    sGp[t] = make_float2(fsig(g0), lo_half ? ftanh_(g1) : fsig(g1));
    __syncthreads();
    if (lo_half) {  // waves 0,1: cell update for hidden index t
      float2 ig = sGp[t];        // (i, g)
      float2 fo = sGp[t + 128];  // (f, o)
      c = fmaf(fo.x, c, ig.x * ig.y);
      sH[t] = fo.y * ftanh_(c);
    }
    __syncthreads();
    vh = ((const float2*)sH)[lane];  // conflict-free (2-way = free)
  }

  // Epilogue: out[b] = (h @ W1.T + b1) @ W2.T + b2, on wave 0.
  if (t < 64) {
    float a = b1[t];
#pragma unroll
    for (int k = 0; k < 128; ++k) a = fmaf(W1[t * 128 + k], sH[k], a);
    float v = a * W2[t];
#pragma unroll
    for (int off = 32; off > 0; off >>= 1) v += __shfl_down(v, off);
    if (t == 0) out[b] = v + b2[0];
  }
}

extern "C" void kernel_launch(void* const* d_in, const int* in_sizes, int n_in,
                              void* d_out, int out_size, void* d_ws, size_t ws_size,
                              hipStream_t stream) {
  const float* x    = (const float*)d_in[0];
  // d_in[1] is the unused python scalar `data`
  const float* Wih1 = (const float*)d_in[2];
  const float* Whh1 = (const float*)d_in[3];
  const float* bih1 = (const float*)d_in[4];
  const float* bhh1 = (const float*)d_in[5];
  const float* Wih2 = (const float*)d_in[6];
  const float* Whh2 = (const float*)d_in[7];
  const float* bih2 = (const float*)d_in[8];
  const float* bhh2 = (const float*)d_in[9];
  const float* W1   = (const float*)d_in[10];
  const float* b1   = (const float*)d_in[11];
  const float* W2   = (const float*)d_in[12];
  const float* b2   = (const float*)d_in[13];
  float* out = (float*)d_out;

  float* h1 = (float*)d_ws;  // 256*1024*8 fp32 = 8 MB scratch

  lstm1_kernel<<<1024, 256, 0, stream>>>(x, Wih1, Whh1, bih1, bhh1, h1);
  lstm2_kernel<<<256, 256, 0, stream>>>(h1, Wih2, Whh2, bih2, bhh2,
                                        W1, b1, W2, b2, out);
}

// Round 3
// 1667.672 us; speedup vs baseline: 1.1338x; 1.1338x over previous
//
#include <hip/hip_runtime.h>
#include <cstdint>

// Fast activations: ~2-ulp exp/div is plenty vs the 1e-3 absmax threshold.
__device__ __forceinline__ float fsig(float x) {
  x = fminf(fmaxf(x, -30.f), 30.f);
  return __fdividef(1.f, 1.f + __expf(-x));
}
__device__ __forceinline__ float ftanh_(float x) {
  x = fminf(fmaxf(x, -15.f), 15.f);
  float e = __expf(2.f * x);
  return __fdividef(e - 1.f, e + 1.f);
}

// Wave-wide broadcast: VGPR lane -> SGPR (VALU pipe, 2 cyc, no LDS traffic).
__device__ __forceinline__ float rl(float v, int lane) {
  return __int_as_float(__builtin_amdgcn_readlane(__float_as_int(v), lane));
}

// ---------------------------------------------------------------------------
// Layer 1: 262144 independent LSTM chains, seq=16, input=1, hidden=8.
// TWO chains per thread: each LDS weight broadcast is amortized over 2 chains
// (halves the LDS-broadcast bytes/chain that bound R1's version).
// ---------------------------------------------------------------------------
__global__ __launch_bounds__(256) void lstm1_kernel(
    const float* __restrict__ x, const float* __restrict__ Wih,
    const float* __restrict__ Whh, const float* __restrict__ bih,
    const float* __restrict__ bhh, float* __restrict__ h1) {
  __shared__ float sWih[32], sB[32], sWhh[256];
  const int tid = threadIdx.x;
  if (tid < 32) { sWih[tid] = Wih[tid]; sB[tid] = bih[tid] + bhh[tid]; }
  sWhh[tid] = Whh[tid];
  __syncthreads();

  const int n0 = blockIdx.x * 512 + tid;  // chain ids
  const int n1 = n0 + 256;

  float xv0[16], xv1[16];
  {
    const float4* xp0 = (const float4*)(x + (size_t)n0 * 16);
    const float4* xp1 = (const float4*)(x + (size_t)n1 * 16);
#pragma unroll
    for (int i = 0; i < 4; ++i) {
      float4 a = xp0[i];
      xv0[4 * i] = a.x; xv0[4 * i + 1] = a.y; xv0[4 * i + 2] = a.z; xv0[4 * i + 3] = a.w;
      float4 b = xp1[i];
      xv1[4 * i] = b.x; xv1[4 * i + 1] = b.y; xv1[4 * i + 2] = b.z; xv1[4 * i + 3] = b.w;
    }
  }
  float h0[8], c0[8], h1a[8], c1a[8];
#pragma unroll
  for (int k = 0; k < 8; ++k) { h0[k] = c0[k] = h1a[k] = c1a[k] = 0.f; }

#pragma unroll
  for (int t = 0; t < 16; ++t) {
    float hn0[8], hn1[8];
#pragma unroll
    for (int k = 0; k < 8; ++k) {
      float acc0[4], acc1[4];  // i,f,g,o rows for hidden index k
#pragma unroll
      for (int gi = 0; gi < 4; ++gi) {
        const int r = gi * 8 + k;
        float wih = sWih[r], bb = sB[r];
        float a0 = fmaf(wih, xv0[t], bb);
        float a1 = fmaf(wih, xv1[t], bb);
#pragma unroll
        for (int j = 0; j < 8; ++j) {
          float w = sWhh[r * 8 + j];
          a0 = fmaf(w, h0[j], a0);
          a1 = fmaf(w, h1a[j], a1);
        }
        acc0[gi] = a0; acc1[gi] = a1;
      }
      {
        float iv = fsig(acc0[0]), fv = fsig(acc0[1]);
        float gv = ftanh_(acc0[2]), ov = fsig(acc0[3]);
        c0[k] = fmaf(fv, c0[k], iv * gv);
        hn0[k] = ov * ftanh_(c0[k]);
      }
      {
        float iv = fsig(acc1[0]), fv = fsig(acc1[1]);
        float gv = ftanh_(acc1[2]), ov = fsig(acc1[3]);
        c1a[k] = fmaf(fv, c1a[k], iv * gv);
        hn1[k] = ov * ftanh_(c1a[k]);
      }
    }
#pragma unroll
    for (int k = 0; k < 8; ++k) { h0[k] = hn0[k]; h1a[k] = hn1[k]; }
  }
  float4* op0 = (float4*)(h1 + (size_t)n0 * 8);
  op0[0] = make_float4(h0[0], h0[1], h0[2], h0[3]);
  op0[1] = make_float4(h0[4], h0[5], h0[6], h0[7]);
  float4* op1 = (float4*)(h1 + (size_t)n1 * 8);
  op1[0] = make_float4(h1a[0], h1a[1], h1a[2], h1a[3]);
  op1[1] = make_float4(h1a[4], h1a[5], h1a[6], h1a[7]);
}

// ---------------------------------------------------------------------------
// Layer 2: B=256 recurrences -> 1 block (512 thr, 8 waves) per CU.
// Thread t owns gate row t: 128 W_hh weights in REGISTERS (<=256 VGPR cap).
// h broadcast via v_readlane->SGPR (VALU pipe), NOT LDS (LDS return BW was
// the R1 wall) and NOT 2 rows/thread (256 weight VGPRs spilled in R2).
// Single barrier/step: activated gates go to a double-buffered LDS array;
// every wave redundantly updates its own register copy of (h, c).
// x-part addresses are block-uniform -> scalar loads, prefetched 1 step.
// ---------------------------------------------------------------------------
__global__ __launch_bounds__(512, 2) void lstm2_kernel(
    const float* __restrict__ h1, const float* __restrict__ Wih,
    const float* __restrict__ Whh, const float* __restrict__ bih,
    const float* __restrict__ bhh, const float* __restrict__ W1,
    const float* __restrict__ b1, const float* __restrict__ W2,
    const float* __restrict__ b2, float* __restrict__ out) {
  __shared__ float sG[2][512];  // activated gates, double-buffered
  const int b = blockIdx.x;
  const int t = threadIdx.x;
  const int lane = t & 63;
  const int gateid = t >> 7;  // 0:i 1:f 2:g 3:o — wave-uniform

  // Weight row t in registers: scalar element assigns (no punning -> SROA ok)
  float w[128];
  {
    const float4* Wr = (const float4*)(Whh + (size_t)t * 128);
#pragma unroll
    for (int i = 0; i < 32; ++i) {
      float4 v = Wr[i];
      w[4 * i] = v.x; w[4 * i + 1] = v.y; w[4 * i + 2] = v.z; w[4 * i + 3] = v.w;
    }
  }
  float wi[8];
  {
    const float4* I = (const float4*)(Wih + (size_t)t * 8);
    float4 a = I[0], bb = I[1];
    wi[0] = a.x; wi[1] = a.y; wi[2] = a.z; wi[3] = a.w;
    wi[4] = bb.x; wi[5] = bb.y; wi[6] = bb.z; wi[7] = bb.w;
  }
  const float bias = bih[t] + bhh[t];

  const float* __restrict__ xbase = h1 + (size_t)b * 8192;  // [1024][8]

  // Every wave keeps a full (h, c) copy: lane l holds indices 2l, 2l+1.
  float2 vh = make_float2(0.f, 0.f);
  float2 vc = make_float2(0.f, 0.f);

  float xs[8];
#pragma unroll
  for (int j = 0; j < 8; ++j) xs[j] = xbase[j];  // uniform -> s_load

  for (int tstep = 0; tstep < 1024; ++tstep) {
    // prefetch next step's x (uniform scalar loads)
    const float* xnp = xbase + ((tstep + 1) & 1023) * 8;
    float xn[8];
#pragma unroll
    for (int j = 0; j < 8; ++j) xn[j] = xnp[j];

    float a0 = bias, a1 = 0.f;
#pragma unroll
    for (int j = 0; j < 8; ++j) a0 = fmaf(wi[j], xs[j], a0);
#pragma unroll
    for (int l = 0; l < 64; ++l) {  // h-part: readlane broadcast
      a0 = fmaf(w[2 * l], rl(vh.x, l), a0);
      a1 = fmaf(w[2 * l + 1], rl(vh.y, l), a1);
    }
    float acc = a0 + a1;
    const int buf = tstep & 1;
    sG[buf][t] = (gateid == 2) ? ftanh_(acc) : fsig(acc);
    __syncthreads();
    {  // redundant per-wave (h,c) update from activated gate pairs
      const float2* g2 = (const float2*)&sG[buf][0];
      float2 iv = g2[lane];
      float2 fv = g2[64 + lane];
      float2 gv = g2[128 + lane];
      float2 ov = g2[192 + lane];
      vc.x = fmaf(fv.x, vc.x, iv.x * gv.x);
      vc.y = fmaf(fv.y, vc.y, iv.y * gv.y);
      vh.x = ov.x * ftanh_(vc.x);
      vh.y = ov.y * ftanh_(vc.y);
    }
#pragma unroll
    for (int j = 0; j < 8; ++j) xs[j] = xn[j];
  }

  // Epilogue: out[b] = (h @ W1.T + b1) @ W2.T + b2, on wave 0 (has full h).
  if (t < 64) {
    float a = b1[t];
#pragma unroll
    for (int l = 0; l < 64; ++l) {
      a = fmaf(W1[t * 128 + 2 * l], rl(vh.x, l), a);
      a = fmaf(W1[t * 128 + 2 * l + 1], rl(vh.y, l), a);
    }
    float v = a * W2[t];
#pragma unroll
    for (int off = 32; off > 0; off >>= 1) v += __shfl_down(v, off);
    if (t == 0) out[b] = v + b2[0];
  }
}

extern "C" void kernel_launch(void* const* d_in, const int* in_sizes, int n_in,
                              void* d_out, int out_size, void* d_ws, size_t ws_size,
                              hipStream_t stream) {
  const float* x    = (const float*)d_in[0];
  // d_in[1] is the unused python scalar `data`
  const float* Wih1 = (const float*)d_in[2];
  const float* Whh1 = (const float*)d_in[3];
  const float* bih1 = (const float*)d_in[4];
  const float* bhh1 = (const float*)d_in[5];
  const float* Wih2 = (const float*)d_in[6];
  const float* Whh2 = (const float*)d_in[7];
  const float* bih2 = (const float*)d_in[8];
  const float* bhh2 = (const float*)d_in[9];
  const float* W1   = (const float*)d_in[10];
  const float* b1   = (const float*)d_in[11];
  const float* W2   = (const float*)d_in[12];
  const float* b2   = (const float*)d_in[13];
  float* out = (float*)d_out;

  float* h1 = (float*)d_ws;  // 256*1024*8 fp32 = 8 MB scratch

  lstm1_kernel<<<512, 256, 0, stream>>>(x, Wih1, Whh1, bih1, bhh1, h1);
  lstm2_kernel<<<256, 512, 0, stream>>>(h1, Wih2, Whh2, bih2, bhh2,
                                        W1, b1, W2, b2, out);
}

// Round 4
// 1193.601 us; speedup vs baseline: 1.5841x; 1.3972x over previous
//
#include <hip/hip_runtime.h>
#include <cstdint>

typedef _Float16 f16x2 __attribute__((ext_vector_type(2)));

// Fast activations: ~2-ulp exp/div is plenty vs the 1e-3 absmax threshold.
__device__ __forceinline__ float fsig(float x) {
  x = fminf(fmaxf(x, -30.f), 30.f);
  return __fdividef(1.f, 1.f + __expf(-x));
}
__device__ __forceinline__ float ftanh_(float x) {
  x = fminf(fmaxf(x, -15.f), 15.f);
  float e = __expf(2.f * x);
  return __fdividef(e - 1.f, e + 1.f);
}

// ---------------------------------------------------------------------------
// Layer 1: 262144 independent LSTM chains, seq=16, input=1, hidden=8.
// One chain per thread. t-loop NOT unrolled (R3's 16x-unrolled body was ~13K
// instructions -> I$ thrash; that, not FMA, explains 232 us vs 25 us floor).
// Weights read straight from global: addresses are wave-uniform -> s_load on
// the scalar pipe, overlapping VALU; 1.4 KB working set stays in constant L1.
// ---------------------------------------------------------------------------
__global__ __launch_bounds__(256) void lstm1_kernel(
    const float* __restrict__ x, const float* __restrict__ Wih,
    const float* __restrict__ Whh, const float* __restrict__ bih,
    const float* __restrict__ bhh, float* __restrict__ h1) {
  const int n = blockIdx.x * 256 + threadIdx.x;  // chain id = b*S + s
  const float* __restrict__ xp = x + (size_t)n * 16;
  float h[8], c[8];
#pragma unroll
  for (int k = 0; k < 8; ++k) h[k] = c[k] = 0.f;

  for (int t = 0; t < 16; ++t) {  // rolled: keep body I$-resident
    float xv = xp[t];
    float hn[8];
#pragma unroll
    for (int k = 0; k < 8; ++k) {
      float acc[4];
#pragma unroll
      for (int gi = 0; gi < 4; ++gi) {
        const int r = gi * 8 + k;
        float a = fmaf(Wih[r], xv, bih[r] + bhh[r]);
#pragma unroll
        for (int j = 0; j < 8; ++j) a = fmaf(Whh[r * 8 + j], h[j], a);
        acc[gi] = a;
      }
      float iv = fsig(acc[0]), fv = fsig(acc[1]);
      float gv = ftanh_(acc[2]), ov = fsig(acc[3]);
      c[k] = fmaf(fv, c[k], iv * gv);
      hn[k] = ov * ftanh_(c[k]);
    }
#pragma unroll
    for (int k = 0; k < 8; ++k) h[k] = hn[k];
  }
  float4* op = (float4*)(h1 + (size_t)n * 8);
  op[0] = make_float4(h[0], h[1], h[2], h[3]);
  op[1] = make_float4(h[4], h[5], h[6], h[7]);
}

// ---------------------------------------------------------------------------
// Layer 2: B=256 recurrences -> 1 block (512 thr) per batch, 2 blocks/CU.
// Thread t owns gate row t. W_hh row packed into 64 half2 VGPRs and PINNED
// with empty asm (+v) so the compiler cannot re-sink the loads (the R2/R3
// failure: VGPR_Count 80, loads rematerialized in-loop every step).
// h lives lane-distributed as packed half2; v_readlane broadcasts 2 h values
// per instruction into v_dot2_f32_f16 (fp32 accum). Gates go through a
// double-buffered LDS array; every wave redundantly updates its own (c,h)
// replica -> ONE barrier per step. x-part: uniform s_loads, fp32, prefetched.
// ---------------------------------------------------------------------------
__global__ __launch_bounds__(512, 4) void lstm2_kernel(
    const float* __restrict__ h1, const float* __restrict__ Wih,
    const float* __restrict__ Whh, const float* __restrict__ bih,
    const float* __restrict__ bhh, const float* __restrict__ W1,
    const float* __restrict__ b1, const float* __restrict__ W2,
    const float* __restrict__ b2, float* __restrict__ out) {
  __shared__ float sG[2][4][128];  // [buf][gate i,f,g,o][hidden k]
  const int b = blockIdx.x;
  const int t = threadIdx.x;
  const int lane = t & 63;
  const int gate = t >> 7;  // 0:i 1:f 2:g 3:o — wave-uniform

  // --- W_hh row t as 64 packed half2, asm-pinned into VGPRs ---
  int w2[64];
  {
    const float2* Wr = (const float2*)(Whh + (size_t)t * 128);
#pragma unroll
    for (int i = 0; i < 64; ++i) {
      float2 v = Wr[i];
      f16x2 p;
      p.x = (_Float16)v.x;
      p.y = (_Float16)v.y;
      w2[i] = __builtin_bit_cast(int, p);
    }
  }
#pragma unroll
  for (int i = 0; i < 64; i += 8)
    asm volatile("" : "+v"(w2[i]), "+v"(w2[i + 1]), "+v"(w2[i + 2]),
                      "+v"(w2[i + 3]), "+v"(w2[i + 4]), "+v"(w2[i + 5]),
                      "+v"(w2[i + 6]), "+v"(w2[i + 7]));

  float wi[8];
  {
    const float4* I = (const float4*)(Wih + (size_t)t * 8);
    float4 a = I[0], bb = I[1];
    wi[0] = a.x; wi[1] = a.y; wi[2] = a.z; wi[3] = a.w;
    wi[4] = bb.x; wi[5] = bb.y; wi[6] = bb.z; wi[7] = bb.w;
  }
  asm volatile("" : "+v"(wi[0]), "+v"(wi[1]), "+v"(wi[2]), "+v"(wi[3]),
                    "+v"(wi[4]), "+v"(wi[5]), "+v"(wi[6]), "+v"(wi[7]));
  const float bias = bih[t] + bhh[t];
  const float* __restrict__ xbase = h1 + (size_t)b * 8192;  // [1024][8]

  // replicated per-wave state: lane holds h[2*lane], h[2*lane+1] (f16 packed)
  f16x2 h2; h2.x = (_Float16)0.f; h2.y = (_Float16)0.f;
  float cx = 0.f, cy = 0.f;

  float xs[8];
#pragma unroll
  for (int j = 0; j < 8; ++j) xs[j] = xbase[j];  // uniform -> s_load

  for (int ts = 0; ts < 1024; ++ts) {
    // prefetch next step's x (uniform scalar loads)
    const float* xn_p = xbase + ((ts + 1) & 1023) * 8;
    float xn[8];
#pragma unroll
    for (int j = 0; j < 8; ++j) xn[j] = xn_p[j];

    float a0 = bias, a1 = 0.f, a2 = 0.f, a3 = 0.f;
#pragma unroll
    for (int j = 0; j < 8; ++j) a0 = fmaf(wi[j], xs[j], a0);

    const int h2i = __builtin_bit_cast(int, h2);
#pragma unroll
    for (int l = 0; l < 64; l += 4) {  // readlane bcast + dot2, 4-way ILP
      a0 = __builtin_amdgcn_fdot2(
          __builtin_bit_cast(f16x2, w2[l]),
          __builtin_bit_cast(f16x2, __builtin_amdgcn_readlane(h2i, l)), a0, false);
      a1 = __builtin_amdgcn_fdot2(
          __builtin_bit_cast(f16x2, w2[l + 1]),
          __builtin_bit_cast(f16x2, __builtin_amdgcn_readlane(h2i, l + 1)), a1, false);
      a2 = __builtin_amdgcn_fdot2(
          __builtin_bit_cast(f16x2, w2[l + 2]),
          __builtin_bit_cast(f16x2, __builtin_amdgcn_readlane(h2i, l + 2)), a2, false);
      a3 = __builtin_amdgcn_fdot2(
          __builtin_bit_cast(f16x2, w2[l + 3]),
          __builtin_bit_cast(f16x2, __builtin_amdgcn_readlane(h2i, l + 3)), a3, false);
    }
    float acc = (a0 + a1) + (a2 + a3);
    float act = (gate == 2) ? ftanh_(acc) : fsig(acc);
    const int buf = ts & 1;
    sG[buf][gate][t & 127] = act;
    __syncthreads();  // the only barrier per step (sG double-buffered)
    {
      float2 iv = *(const float2*)&sG[buf][0][2 * lane];
      float2 fv = *(const float2*)&sG[buf][1][2 * lane];
      float2 gv = *(const float2*)&sG[buf][2][2 * lane];
      float2 ov = *(const float2*)&sG[buf][3][2 * lane];
      cx = fmaf(fv.x, cx, iv.x * gv.x);
      cy = fmaf(fv.y, cy, iv.y * gv.y);
      h2.x = (_Float16)(ov.x * ftanh_(cx));
      h2.y = (_Float16)(ov.y * ftanh_(cy));
    }
#pragma unroll
    for (int j = 0; j < 8; ++j) xs[j] = xn[j];
  }

  // Epilogue: out[b] = (h @ W1.T + b1) @ W2.T + b2, wave 0 (has full h).
  if (t < 64) {
    const float2* w1r = (const float2*)(W1 + (size_t)t * 128);
    float a = b1[t];
    const int h2i = __builtin_bit_cast(int, h2);
#pragma unroll
    for (int l = 0; l < 64; ++l) {
      float2 wv = w1r[l];
      f16x2 ww;
      ww.x = (_Float16)wv.x;
      ww.y = (_Float16)wv.y;
      a = __builtin_amdgcn_fdot2(
          ww, __builtin_bit_cast(f16x2, __builtin_amdgcn_readlane(h2i, l)), a, false);
    }
    float v = a * W2[t];
#pragma unroll
    for (int off = 32; off > 0; off >>= 1) v += __shfl_down(v, off);
    if (t == 0) out[b] = v + b2[0];
  }
}

extern "C" void kernel_launch(void* const* d_in, const int* in_sizes, int n_in,
                              void* d_out, int out_size, void* d_ws, size_t ws_size,
                              hipStream_t stream) {
  const float* x    = (const float*)d_in[0];
  // d_in[1] is the unused python scalar `data`
  const float* Wih1 = (const float*)d_in[2];
  const float* Whh1 = (const float*)d_in[3];
  const float* bih1 = (const float*)d_in[4];
  const float* bhh1 = (const float*)d_in[5];
  const float* Wih2 = (const float*)d_in[6];
  const float* Whh2 = (const float*)d_in[7];
  const float* bih2 = (const float*)d_in[8];
  const float* bhh2 = (const float*)d_in[9];
  const float* W1   = (const float*)d_in[10];
  const float* b1   = (const float*)d_in[11];
  const float* W2   = (const float*)d_in[12];
  const float* b2   = (const float*)d_in[13];
  float* out = (float*)d_out;

  float* h1 = (float*)d_ws;  // 256*1024*8 fp32 = 8 MB scratch

  lstm1_kernel<<<1024, 256, 0, stream>>>(x, Wih1, Whh1, bih1, bhh1, h1);
  lstm2_kernel<<<256, 512, 0, stream>>>(h1, Wih2, Whh2, bih2, bhh2,
                                        W1, b1, W2, b2, out);
}